// Round 14
// baseline (5106.650 us; speedup 1.0000x reference)
//
#include <hip/hip_runtime.h>

#define NN 8192
#define DD 32
// stagger-padded LDS index: +4 floats of pad per 16 (keeps 16B alignment)
#define SIDX(c) ((c) + 4 * ((c) >> 4))

constexpr float kEps   = 0.1f;
constexpr float kStab  = 1e-8f;
constexpr float kMass  = 1.0f / 8192.0f;     // mu = nu = 1/n
constexpr float kInvSc = 1.0f / 256.0f;      // K stored as fp8 of 256*K
constexpr float kLnSc  = 5.545177444479562f; // ln(256)

typedef float v2f __attribute__((ext_vector_type(2)));

__device__ inline void cvt16v2(uint4 kk, v2f* f) {
    f[0] = __builtin_amdgcn_cvt_pk_f32_fp8(kk.x, false);
    f[1] = __builtin_amdgcn_cvt_pk_f32_fp8(kk.x, true);
    f[2] = __builtin_amdgcn_cvt_pk_f32_fp8(kk.y, false);
    f[3] = __builtin_amdgcn_cvt_pk_f32_fp8(kk.y, true);
    f[4] = __builtin_amdgcn_cvt_pk_f32_fp8(kk.z, false);
    f[5] = __builtin_amdgcn_cvt_pk_f32_fp8(kk.z, true);
    f[6] = __builtin_amdgcn_cvt_pk_f32_fp8(kk.w, false);
    f[7] = __builtin_amdgcn_cvt_pk_f32_fp8(kk.w, true);
}
__device__ inline unsigned int pack8x4(float a, float b, float c, float d) {
    int v = 0;
    v = __builtin_amdgcn_cvt_pk_fp8_f32(a, b, v, false);
    v = __builtin_amdgcn_cvt_pk_fp8_f32(c, d, v, true);
    return (unsigned int)v;
}
// pack two positive floats to bf16x2 (round-to-nearest-even)
__device__ inline unsigned int bf16pk(float a, float b) {
    unsigned int ua = __float_as_uint(a), ub = __float_as_uint(b);
    ua = (ua + 0x7FFFu + ((ua >> 16) & 1u)) >> 16;
    ub = (ub + 0x7FFFu + ((ub >> 16) & 1u)) >> 16;
    return ua | (ub << 16);
}
// packed dot: 16 fp8 x 8 v2f -> scalar (8 v_pk_fma_f32)
__device__ inline float dot16p(uint4 kk, const v2f* vv) {
    v2f f[8];
    cvt16v2(kk, f);
    v2f acc = {0.f, 0.f};
#pragma unroll
    for (int i = 0; i < 8; i++) acc = __builtin_elementwise_fma(f[i], vv[i], acc);
    return acc.x + acc.y;
}
// packed axpy: ca[8] (v2f) += fp8x16 * ur
__device__ inline void axpy16p(uint4 kk, float ur, v2f* ca) {
    v2f f[8];
    cvt16v2(kk, f);
    const v2f u2 = {ur, ur};
#pragma unroll
    for (int i = 0; i < 8; i++) ca[i] = __builtin_elementwise_fma(f[i], u2, ca[i]);
}
// wsum partial for 16 bytes: sum_j v_j * glut[byte_j]  (byte0 = lowest col)
__device__ inline float wsum16(uint4 kk, const v2f* vv, const float* glut) {
    float a = 0.f;
    const unsigned int wd[4] = {kk.x, kk.y, kk.z, kk.w};
#pragma unroll
    for (int j = 0; j < 4; j++) {
        const unsigned int wv = wd[j];
        a = fmaf(vv[2 * j].x,     glut[wv & 255u], a);
        a = fmaf(vv[2 * j].y,     glut[(wv >> 8) & 255u], a);
        a = fmaf(vv[2 * j + 1].x, glut[(wv >> 16) & 255u], a);
        a = fmaf(vv[2 * j + 1].y, glut[wv >> 24], a);
    }
    return a;
}

// -------------------------------- build K8 = fp8(256*exp(-cost/eps)), and fuse
// the initial column sums (u=1): colacc accumulated in registers from the f32 e
// values, block-reduced via LDS (reusing xs), one 64-contender atomicAdd per
// column (round-0-proven benign regime). Batched: grid z selects the pair.
__global__ __launch_bounds__(256) void sk_build_k(const float* __restrict__ src,
                                                  const float* __restrict__ tgt,
                                                  unsigned char* __restrict__ K8,
                                                  float* __restrict__ rc,
                                                  int nb) {
    __shared__ float xs[DD * 160];   // [d][SIDX(row)], row < 128 -> max 155
    __shared__ float ys[DD * 160];
    __shared__ float sx[128], sy[128];
    const int z = blockIdx.z;
    const float* X = src; const float* Y = tgt;
    if (nb == 3) { if (z == 1) Y = src; else if (z == 2) X = tgt; }
    unsigned char* K = K8 + (size_t)z * NN * NN;
    float* rcz = rc + (size_t)z * NN;

    const int t  = threadIdx.x;
    const int r0 = blockIdx.y * 128, c0 = blockIdx.x * 128;

    for (int idx = t; idx < DD * 128; idx += 256) {
        int d = idx >> 7, row = idx & 127;
        xs[d * 160 + SIDX(row)] = X[(size_t)(r0 + row) * DD + d];
        ys[d * 160 + SIDX(row)] = Y[(size_t)(c0 + row) * DD + d];
    }
    __syncthreads();
    if (t < 128) {
        const int si = SIDX(t);
        float s = 0.f;
        for (int d = 0; d < DD; d++) { float v = xs[d * 160 + si]; s = fmaf(v, v, s); }
        sx[t] = s;
    } else {
        const int q = t - 128, si = SIDX(q);
        float s = 0.f;
        for (int d = 0; d < DD; d++) { float v = ys[d * 160 + si]; s = fmaf(v, v, s); }
        sy[q] = s;
    }
    __syncthreads();

    const int tr = t >> 4, tc = t & 15;
    const int xb = SIDX(8 * tr);     // rows 8tr..8tr+7 contiguous in SIDX space
    const int yb = SIDX(8 * tc);
    float acc[8][8] = {};
#pragma unroll 4
    for (int d = 0; d < DD; d++) {
        const float* xrow = &xs[d * 160];
        const float* yrow = &ys[d * 160];
        const float4 xa0 = *reinterpret_cast<const float4*>(&xrow[xb]);
        const float4 xa1 = *reinterpret_cast<const float4*>(&xrow[xb + 4]);
        const float4 yb0 = *reinterpret_cast<const float4*>(&yrow[yb]);
        const float4 yb1 = *reinterpret_cast<const float4*>(&yrow[yb + 4]);
        const float xv[8] = {xa0.x, xa0.y, xa0.z, xa0.w, xa1.x, xa1.y, xa1.z, xa1.w};
        const float yv[8] = {yb0.x, yb0.y, yb0.z, yb0.w, yb1.x, yb1.y, yb1.z, yb1.w};
#pragma unroll
        for (int a = 0; a < 8; a++)
#pragma unroll
            for (int b = 0; b < 8; b++) acc[a][b] = fmaf(xv[a], yv[b], acc[a][b]);
    }
    float colacc[8] = {};
#pragma unroll
    for (int a = 0; a < 8; a++) {
        const int r = r0 + 8 * tr + a;
        const float sxa = sx[8 * tr + a];
        float e[8];
#pragma unroll
        for (int b = 0; b < 8; b++) {
            float cost = sxa + sy[8 * tc + b] - 2.0f * acc[a][b];
            cost = fmaxf(cost, 0.0f);
            e[b] = __expf(fmaf(-10.0f, cost, kLnSc));   // 256 * exp(-cost/eps)
            colacc[b] += e[b];
        }
        uint2 pk;
        pk.x = pack8x4(e[0], e[1], e[2], e[3]);
        pk.y = pack8x4(e[4], e[5], e[6], e[7]);
        *reinterpret_cast<uint2*>(&K[(size_t)r * NN + c0 + 8 * tc]) = pk;
    }
    // fold 16 tr-partials per column via LDS (reuse xs; all xs reads done)
    __syncthreads();
    float* colred = xs;              // [16][128]
#pragma unroll
    for (int b = 0; b < 8; b++) colred[tr * 128 + 8 * tc + b] = colacc[b];
    __syncthreads();
    if (t < 128) {
        float s = 0.f;
#pragma unroll
        for (int q = 0; q < 16; q++) s += colred[q * 128 + t];
        atomicAdd(&rcz[c0 + t], s);
    }
}

// -------------------------------- v[c] = m / (raw[c]/256 + stab)  (once, after build)
__global__ void sk_v(const float* __restrict__ rc, float* __restrict__ v) {
    const int i = (blockIdx.z * gridDim.x + blockIdx.x) * 256 + threadIdx.x;
    v[i] = kMass * __builtin_amdgcn_rcpf(fmaf(rc[i], kInvSc, kStab));
}

// -------------------------------- fused iteration, 64-ROW blocks (grid 128/z):
// same per-group math as the proven round-8/12 kernel (u's per-row reduction
// tree is bit-identical), but each block covers 64 rows (16 groups) and emits
// ONE 8192-col bf16 partial -> 128 partials/z instead of 256. Halves the
// partial stream (drain 12.6->6.3 MB/iter, reduce fold 24.6->12.3 MB) and
// halves block count (384 total = one co-residency wave at 2/CU).
//  - last-iter wsum fusion (LUT, double accum) -- no 4th K pass
//  - direct bf16 drain from registers (coalesced 2KB/wave), PLAIN stores
//    (round-13: nt was null-to-negative -- partials want the L2/L3 round-trip)
// Lessons kept: pragma unroll 1 + 1-deep prefetch (round-4 spill), pk-math
// (round-8), bf16 partials (round-7). Round-9/10: hipLaunchCooperativeKernel
// silently no-ops under graph capture -- kernel boundaries are the only grid sync.
__global__ __launch_bounds__(512, 2) void sk_iter(const unsigned char* __restrict__ K8,
                                                  const float* __restrict__ v_in,
                                                  unsigned short* __restrict__ rcp,
                                                  double* __restrict__ wacc,
                                                  int last) {
    __shared__ float red[16][8][4];    // group x wave x row partial rowsums
    __shared__ float glut[256];        // byte -> f*ln(f/256) (last-iter wsum)
    __shared__ double wred[8];
    const int t = threadIdx.x, lane = t & 63, w = t >> 6;
    const int z = blockIdx.z;
    const unsigned char* K = K8 + (size_t)z * NN * NN;
    const int rowbase = blockIdx.x * 64;
    const int c0 = 1024 * w;

    if (last && t < 256) {
        v2f d = __builtin_amdgcn_cvt_pk_f32_fp8((unsigned int)t, false);
        const float f = d.x;
        glut[t] = (f > 0.f) ? f * __logf(f * kInvSc) : 0.f;
    }   // visible to all by the group-0 __syncthreads below

    // ---- v for this lane's 16 columns, as 8 packed pairs in registers
    v2f vv[8];
    {
        const float* vz = v_in + (size_t)z * NN + c0 + 16 * lane;
        const float4 q0 = reinterpret_cast<const float4*>(vz)[0];
        const float4 q1 = reinterpret_cast<const float4*>(vz)[1];
        const float4 q2 = reinterpret_cast<const float4*>(vz)[2];
        const float4 q3 = reinterpret_cast<const float4*>(vz)[3];
        vv[0] = {q0.x, q0.y}; vv[1] = {q0.z, q0.w};
        vv[2] = {q1.x, q1.y}; vv[3] = {q1.z, q1.w};
        vv[4] = {q2.x, q2.y}; vv[5] = {q2.z, q2.w};
        vv[6] = {q3.x, q3.y}; vv[7] = {q3.z, q3.w};
    }

    const unsigned char* kp = K + (size_t)rowbase * NN + c0 + 16 * lane;
    // prefetch group 0 (4 rows x 16 cols of packed fp8)
    uint4 n0 = *reinterpret_cast<const uint4*>(kp);
    uint4 n1 = *reinterpret_cast<const uint4*>(kp + (size_t)NN);
    uint4 n2 = *reinterpret_cast<const uint4*>(kp + (size_t)2 * NN);
    uint4 n3 = *reinterpret_cast<const uint4*>(kp + (size_t)3 * NN);

    v2f ca[8] = {{0,0},{0,0},{0,0},{0,0},{0,0},{0,0},{0,0},{0,0}};
    double dacc = 0.0;
#pragma unroll 1
    for (int g = 0; g < 16; g++) {
        const uint4 k0 = n0, k1 = n1, k2 = n2, k3 = n3;
        if (g < 15) {   // issue next group's loads before computing on current
            const unsigned char* np = kp + (size_t)(4 * (g + 1)) * NN;
            n0 = *reinterpret_cast<const uint4*>(np);
            n1 = *reinterpret_cast<const uint4*>(np + (size_t)NN);
            n2 = *reinterpret_cast<const uint4*>(np + (size_t)2 * NN);
            n3 = *reinterpret_cast<const uint4*>(np + (size_t)3 * NN);
        }
        // phase 1: per-lane partial row sums -> wave reduce -> LDS
        float p0 = dot16p(k0, vv);
        float p1 = dot16p(k1, vv);
        float p2 = dot16p(k2, vv);
        float p3 = dot16p(k3, vv);
#pragma unroll
        for (int off = 32; off > 0; off >>= 1) {
            p0 += __shfl_down(p0, off);
            p1 += __shfl_down(p1, off);
            p2 += __shfl_down(p2, off);
            p3 += __shfl_down(p3, off);
        }
        if (lane == 0) {
            red[g][w][0] = p0; red[g][w][1] = p1;
            red[g][w][2] = p2; red[g][w][3] = p3;
        }
        __syncthreads();
        // every wave computes u for the 4 rows (identical fp math, no 2nd sync)
        float ug[4];
#pragma unroll
        for (int r = 0; r < 4; r++) {
            float s = 0.f;
#pragma unroll
            for (int ww = 0; ww < 8; ww++) s += red[g][ww][r];
            ug[r] = kMass / (s * kInvSc + kStab);
        }
        if (!last) {
            // phase 2: re-convert the SAME registers, accumulate column partials
            axpy16p(k0, ug[0], ca);
            axpy16p(k1, ug[1], ca);
            axpy16p(k2, ug[2], ca);
            axpy16p(k3, ug[3], ca);
        } else {
            // final iteration: accumulate wsum terms from the same registers
            dacc += (double)ug[0] * (double)wsum16(k0, vv, glut);
            dacc += (double)ug[1] * (double)wsum16(k1, vv, glut);
            dacc += (double)ug[2] * (double)wsum16(k2, vv, glut);
            dacc += (double)ug[3] * (double)wsum16(k3, vv, glut);
        }
    }
    if (last) {
        for (int off = 32; off > 0; off >>= 1) dacc += __shfl_down(dacc, off);
        if (lane == 0) wred[w] = dacc;
        __syncthreads();
        if (t == 0) {
            double tot = 0.0;
#pragma unroll
            for (int i = 0; i < 8; i++) tot += wred[i];
            atomicAdd(&wacc[z], -(double)kEps * (double)kInvSc * tot);
        }
        return;
    }

    // ---- direct drain: pack this lane's 16 contiguous cols to bf16, 2x uint4
    unsigned short* rp = rcp + ((size_t)z * 128 + blockIdx.x) * NN + c0 + 16 * lane;
    uint4 o0, o1;
    o0.x = bf16pk(ca[0].x, ca[0].y); o0.y = bf16pk(ca[1].x, ca[1].y);
    o0.z = bf16pk(ca[2].x, ca[2].y); o0.w = bf16pk(ca[3].x, ca[3].y);
    o1.x = bf16pk(ca[4].x, ca[4].y); o1.y = bf16pk(ca[5].x, ca[5].y);
    o1.z = bf16pk(ca[6].x, ca[6].y); o1.w = bf16pk(ca[7].x, ca[7].y);
    *reinterpret_cast<uint4*>(rp)     = o0;
    *reinterpret_cast<uint4*>(rp + 8) = o1;
}

// -------------------------------- fold 128 bf16 block partials -> v (next iteration)
// thread (g=t&7, q=t>>3): col-group of 8 bf16 cols (one uint4), 4 partial-rows
// -> LDS [32][64] -> 64 lanes fold 32 and emit v.
__global__ __launch_bounds__(256) void sk_reduce(const unsigned short* __restrict__ rcp,
                                                 float* __restrict__ v_out) {
    __shared__ float red[32 * 64];
    const int t = threadIdx.x, g = t & 7, q = t >> 3;
    const int z = blockIdx.z;
    const int c0 = blockIdx.x * 64;
    const unsigned short* base = rcp + (size_t)z * 128 * NN + c0 + 8 * g;
    float acc[8] = {};
#pragma unroll
    for (int r = 0; r < 4; r++) {
        uint4 hv = *reinterpret_cast<const uint4*>(base + (size_t)(4 * q + r) * NN);
        const unsigned int h[4] = {hv.x, hv.y, hv.z, hv.w};
#pragma unroll
        for (int j = 0; j < 4; j++) {
            acc[2 * j]     += __uint_as_float((h[j] & 0xFFFFu) << 16);
            acc[2 * j + 1] += __uint_as_float(h[j] & 0xFFFF0000u);
        }
    }
    float* rw = &red[q * 64 + g * 8];
    *reinterpret_cast<float4*>(rw)     = {acc[0], acc[1], acc[2], acc[3]};
    *reinterpret_cast<float4*>(rw + 4) = {acc[4], acc[5], acc[6], acc[7]};
    __syncthreads();
    if (t < 64) {
        float s = 0.f;
#pragma unroll 8
        for (int q2 = 0; q2 < 32; q2++) s += red[q2 * 64 + t];
        v_out[(size_t)z * NN + c0 + t] =
            kMass * __builtin_amdgcn_rcpf(fmaf(s, kInvSc, kStab));
    }
}

// ------------------------------------------------- combine
__global__ void sk_combine(const double* __restrict__ acc, float* __restrict__ out) {
    if (threadIdx.x == 0)
        out[0] = (float)((acc[0] - 0.5 * acc[1] - 0.5 * acc[2]) / 8192.0);
}

extern "C" void kernel_launch(void* const* d_in, const int* in_sizes, int n_in,
                              void* d_out, int out_size, void* d_ws, size_t ws_size,
                              hipStream_t stream) {
    const float* src = (const float*)d_in[0];
    const float* tgt = (const float*)d_in[1];
    float* out = (float*)d_out;
    char* ws = (char*)d_ws;

    // batched needs: 3 K matrices + 3x128x8192 bf16 partials + vectors
    const size_t need3 = 3ull * NN * NN + 3ull * 128 * NN * 2 + 8ull * NN * 4 + 1024;
    const bool batched = ws_size >= need3;
    const int B = batched ? 3 : 1;

    unsigned char*  K8  = (unsigned char*)ws;
    unsigned short* rcp = (unsigned short*)(ws + (size_t)B * NN * NN);
    float*  vb   = (float*)((char*)rcp + (size_t)B * 128 * NN * 2);
    float*  rc0  = vb + (size_t)B * NN;
    double* wacc = (double*)(rc0 + (size_t)B * NN);

    hipMemsetAsync(wacc, 0, 3 * sizeof(double), stream);

    if (batched) {
        hipMemsetAsync(rc0, 0, 3ull * NN * sizeof(float), stream);
        sk_build_k<<<dim3(64, 64, 3), 256, 0, stream>>>(src, tgt, K8, rc0, 3);
        sk_v<<<dim3(32, 1, 3), 256, 0, stream>>>(rc0, vb);           // v_1
        for (int t = 1; t <= 100; t++) {
            sk_iter<<<dim3(128, 1, 3), 512, 0, stream>>>(K8, vb, rcp, wacc,
                                                         t == 100 ? 1 : 0);
            if (t < 100)
                sk_reduce<<<dim3(128, 1, 3), 256, 0, stream>>>(rcp, vb);
        }
        // last sk_iter accumulated the transport costs into wacc[0..2]
    } else {
        const float* pts[3][2] = {{src, tgt}, {src, src}, {tgt, tgt}};
        for (int tf = 0; tf < 3; tf++) {
            hipMemsetAsync(rc0, 0, 1ull * NN * sizeof(float), stream);
            sk_build_k<<<dim3(64, 64, 1), 256, 0, stream>>>(pts[tf][0], pts[tf][1],
                                                            K8, rc0, 1);
            sk_v<<<dim3(32, 1, 1), 256, 0, stream>>>(rc0, vb);
            for (int t = 1; t <= 100; t++) {
                sk_iter<<<dim3(128, 1, 1), 512, 0, stream>>>(K8, vb, rcp, &wacc[tf],
                                                             t == 100 ? 1 : 0);
                if (t < 100)
                    sk_reduce<<<dim3(128, 1, 1), 256, 0, stream>>>(rcp, vb);
            }
        }
    }
    sk_combine<<<1, 64, 0, stream>>>(wacc, out);
}

// Round 15
// 4622.615 us; speedup vs baseline: 1.1047x; 1.1047x over previous
//
#include <hip/hip_runtime.h>

#define NN 8192
#define DD 32
// stagger-padded LDS index: +4 floats of pad per 16 (keeps 16B alignment)
#define SIDX(c) ((c) + 4 * ((c) >> 4))

constexpr float kEps   = 0.1f;
constexpr float kStab  = 1e-8f;
constexpr float kMass  = 1.0f / 8192.0f;     // mu = nu = 1/n
constexpr float kInvSc = 1.0f / 256.0f;      // K stored as fp8 of 256*K
constexpr float kLnSc  = 5.545177444479562f; // ln(256)

typedef float v2f __attribute__((ext_vector_type(2)));

__device__ inline void cvt16v2(uint4 kk, v2f* f) {
    f[0] = __builtin_amdgcn_cvt_pk_f32_fp8(kk.x, false);
    f[1] = __builtin_amdgcn_cvt_pk_f32_fp8(kk.x, true);
    f[2] = __builtin_amdgcn_cvt_pk_f32_fp8(kk.y, false);
    f[3] = __builtin_amdgcn_cvt_pk_f32_fp8(kk.y, true);
    f[4] = __builtin_amdgcn_cvt_pk_f32_fp8(kk.z, false);
    f[5] = __builtin_amdgcn_cvt_pk_f32_fp8(kk.z, true);
    f[6] = __builtin_amdgcn_cvt_pk_f32_fp8(kk.w, false);
    f[7] = __builtin_amdgcn_cvt_pk_f32_fp8(kk.w, true);
}
__device__ inline unsigned int pack8x4(float a, float b, float c, float d) {
    int v = 0;
    v = __builtin_amdgcn_cvt_pk_fp8_f32(a, b, v, false);
    v = __builtin_amdgcn_cvt_pk_fp8_f32(c, d, v, true);
    return (unsigned int)v;
}
// pack two positive floats to bf16x2 (round-to-nearest-even)
__device__ inline unsigned int bf16pk(float a, float b) {
    unsigned int ua = __float_as_uint(a), ub = __float_as_uint(b);
    ua = (ua + 0x7FFFu + ((ua >> 16) & 1u)) >> 16;
    ub = (ub + 0x7FFFu + ((ub >> 16) & 1u)) >> 16;
    return ua | (ub << 16);
}
// packed dot: 16 fp8 x 8 v2f -> scalar (8 v_pk_fma_f32)
__device__ inline float dot16p(uint4 kk, const v2f* vv) {
    v2f f[8];
    cvt16v2(kk, f);
    v2f acc = {0.f, 0.f};
#pragma unroll
    for (int i = 0; i < 8; i++) acc = __builtin_elementwise_fma(f[i], vv[i], acc);
    return acc.x + acc.y;
}
// packed axpy: ca[8] (v2f) += fp8x16 * ur
__device__ inline void axpy16p(uint4 kk, float ur, v2f* ca) {
    v2f f[8];
    cvt16v2(kk, f);
    const v2f u2 = {ur, ur};
#pragma unroll
    for (int i = 0; i < 8; i++) ca[i] = __builtin_elementwise_fma(f[i], u2, ca[i]);
}
// wsum partial for 16 bytes: sum_j v_j * glut[byte_j]  (byte0 = lowest col)
__device__ inline float wsum16(uint4 kk, const v2f* vv, const float* glut) {
    float a = 0.f;
    const unsigned int wd[4] = {kk.x, kk.y, kk.z, kk.w};
#pragma unroll
    for (int j = 0; j < 4; j++) {
        const unsigned int wv = wd[j];
        a = fmaf(vv[2 * j].x,     glut[wv & 255u], a);
        a = fmaf(vv[2 * j].y,     glut[(wv >> 8) & 255u], a);
        a = fmaf(vv[2 * j + 1].x, glut[(wv >> 16) & 255u], a);
        a = fmaf(vv[2 * j + 1].y, glut[wv >> 24], a);
    }
    return a;
}

// -------------------------------- build K8 = fp8(256*exp(-cost/eps)), and fuse
// the initial column sums (u=1): colacc accumulated in registers from the f32 e
// values, block-reduced via LDS (reusing xs), one 64-contender atomicAdd per
// column (round-0-proven benign regime). Batched: grid z selects the pair.
__global__ __launch_bounds__(256) void sk_build_k(const float* __restrict__ src,
                                                  const float* __restrict__ tgt,
                                                  unsigned char* __restrict__ K8,
                                                  float* __restrict__ rc,
                                                  int nb) {
    __shared__ float xs[DD * 160];   // [d][SIDX(row)], row < 128 -> max 155
    __shared__ float ys[DD * 160];
    __shared__ float sx[128], sy[128];
    const int z = blockIdx.z;
    const float* X = src; const float* Y = tgt;
    if (nb == 3) { if (z == 1) Y = src; else if (z == 2) X = tgt; }
    unsigned char* K = K8 + (size_t)z * NN * NN;
    float* rcz = rc + (size_t)z * NN;

    const int t  = threadIdx.x;
    const int r0 = blockIdx.y * 128, c0 = blockIdx.x * 128;

    for (int idx = t; idx < DD * 128; idx += 256) {
        int d = idx >> 7, row = idx & 127;
        xs[d * 160 + SIDX(row)] = X[(size_t)(r0 + row) * DD + d];
        ys[d * 160 + SIDX(row)] = Y[(size_t)(c0 + row) * DD + d];
    }
    __syncthreads();
    if (t < 128) {
        const int si = SIDX(t);
        float s = 0.f;
        for (int d = 0; d < DD; d++) { float v = xs[d * 160 + si]; s = fmaf(v, v, s); }
        sx[t] = s;
    } else {
        const int q = t - 128, si = SIDX(q);
        float s = 0.f;
        for (int d = 0; d < DD; d++) { float v = ys[d * 160 + si]; s = fmaf(v, v, s); }
        sy[q] = s;
    }
    __syncthreads();

    const int tr = t >> 4, tc = t & 15;
    const int xb = SIDX(8 * tr);     // rows 8tr..8tr+7 contiguous in SIDX space
    const int yb = SIDX(8 * tc);
    float acc[8][8] = {};
#pragma unroll 4
    for (int d = 0; d < DD; d++) {
        const float* xrow = &xs[d * 160];
        const float* yrow = &ys[d * 160];
        const float4 xa0 = *reinterpret_cast<const float4*>(&xrow[xb]);
        const float4 xa1 = *reinterpret_cast<const float4*>(&xrow[xb + 4]);
        const float4 yb0 = *reinterpret_cast<const float4*>(&yrow[yb]);
        const float4 yb1 = *reinterpret_cast<const float4*>(&yrow[yb + 4]);
        const float xv[8] = {xa0.x, xa0.y, xa0.z, xa0.w, xa1.x, xa1.y, xa1.z, xa1.w};
        const float yv[8] = {yb0.x, yb0.y, yb0.z, yb0.w, yb1.x, yb1.y, yb1.z, yb1.w};
#pragma unroll
        for (int a = 0; a < 8; a++)
#pragma unroll
            for (int b = 0; b < 8; b++) acc[a][b] = fmaf(xv[a], yv[b], acc[a][b]);
    }
    float colacc[8] = {};
#pragma unroll
    for (int a = 0; a < 8; a++) {
        const int r = r0 + 8 * tr + a;
        const float sxa = sx[8 * tr + a];
        float e[8];
#pragma unroll
        for (int b = 0; b < 8; b++) {
            float cost = sxa + sy[8 * tc + b] - 2.0f * acc[a][b];
            cost = fmaxf(cost, 0.0f);
            e[b] = __expf(fmaf(-10.0f, cost, kLnSc));   // 256 * exp(-cost/eps)
            colacc[b] += e[b];
        }
        uint2 pk;
        pk.x = pack8x4(e[0], e[1], e[2], e[3]);
        pk.y = pack8x4(e[4], e[5], e[6], e[7]);
        *reinterpret_cast<uint2*>(&K[(size_t)r * NN + c0 + 8 * tc]) = pk;
    }
    // fold 16 tr-partials per column via LDS (reuse xs; all xs reads done)
    __syncthreads();
    float* colred = xs;              // [16][128]
#pragma unroll
    for (int b = 0; b < 8; b++) colred[tr * 128 + 8 * tc + b] = colacc[b];
    __syncthreads();
    if (t < 128) {
        float s = 0.f;
#pragma unroll
        for (int q = 0; q < 16; q++) s += colred[q * 128 + t];
        atomicAdd(&rcz[c0 + t], s);
    }
}

// -------------------------------- v[c] = m / (raw[c]/256 + stab)  (once, after build)
__global__ void sk_v(const float* __restrict__ rc, float* __restrict__ v) {
    const int i = (blockIdx.z * gridDim.x + blockIdx.x) * 256 + threadIdx.x;
    v[i] = kMass * __builtin_amdgcn_rcpf(fmaf(rc[i], kInvSc, kStab));
}

// -------------------------------- fused iteration (round-8 proven math) with:
//  - last-iter wsum fusion (LUT, double accum) -- removed sk_wsum's 4th K pass
//  - u stores removed (dead after wsum fusion)
//  - DIRECT bf16 partial drain: each lane owns 16 contiguous cols; pack+store
//    2x uint4 straight from registers (coalesced 2KB/wave), PLAIN stores
//    (round-13: nt was null-to-negative; round-14: 64-row blocks regressed --
//    32-row blocks at 768 total keep 2+ blocks/CU for barrier-latency hiding).
// Lessons kept: pragma unroll 1 + 1-deep prefetch (round-4 spill), pk-math
// (round-8), bf16 partials (round-7). Round-9/10: hipLaunchCooperativeKernel
// silently no-ops under graph capture -- kernel boundaries are the only grid sync.
__global__ __launch_bounds__(512, 2) void sk_iter(const unsigned char* __restrict__ K8,
                                                  const float* __restrict__ v_in,
                                                  unsigned short* __restrict__ rcp,
                                                  double* __restrict__ wacc,
                                                  int last) {
    __shared__ float red[8][8][4];     // group x wave x row partial rowsums
    __shared__ float glut[256];        // byte -> f*ln(f/256) (last-iter wsum)
    __shared__ double wred[8];
    const int t = threadIdx.x, lane = t & 63, w = t >> 6;
    const int z = blockIdx.z;
    const unsigned char* K = K8 + (size_t)z * NN * NN;
    const int rowbase = blockIdx.x * 32;
    const int c0 = 1024 * w;

    if (last && t < 256) {
        v2f d = __builtin_amdgcn_cvt_pk_f32_fp8((unsigned int)t, false);
        const float f = d.x;
        glut[t] = (f > 0.f) ? f * __logf(f * kInvSc) : 0.f;
    }   // visible to all by the group-0 __syncthreads below

    // ---- v for this lane's 16 columns, as 8 packed pairs in registers
    v2f vv[8];
    {
        const float* vz = v_in + (size_t)z * NN + c0 + 16 * lane;
        const float4 q0 = reinterpret_cast<const float4*>(vz)[0];
        const float4 q1 = reinterpret_cast<const float4*>(vz)[1];
        const float4 q2 = reinterpret_cast<const float4*>(vz)[2];
        const float4 q3 = reinterpret_cast<const float4*>(vz)[3];
        vv[0] = {q0.x, q0.y}; vv[1] = {q0.z, q0.w};
        vv[2] = {q1.x, q1.y}; vv[3] = {q1.z, q1.w};
        vv[4] = {q2.x, q2.y}; vv[5] = {q2.z, q2.w};
        vv[6] = {q3.x, q3.y}; vv[7] = {q3.z, q3.w};
    }

    const unsigned char* kp = K + (size_t)rowbase * NN + c0 + 16 * lane;
    // prefetch group 0 (4 rows x 16 cols of packed fp8)
    uint4 n0 = *reinterpret_cast<const uint4*>(kp);
    uint4 n1 = *reinterpret_cast<const uint4*>(kp + (size_t)NN);
    uint4 n2 = *reinterpret_cast<const uint4*>(kp + (size_t)2 * NN);
    uint4 n3 = *reinterpret_cast<const uint4*>(kp + (size_t)3 * NN);

    v2f ca[8] = {{0,0},{0,0},{0,0},{0,0},{0,0},{0,0},{0,0},{0,0}};
    double dacc = 0.0;
#pragma unroll 1
    for (int g = 0; g < 8; g++) {
        const uint4 k0 = n0, k1 = n1, k2 = n2, k3 = n3;
        if (g < 7) {   // issue next group's loads before computing on current
            const unsigned char* np = kp + (size_t)(4 * (g + 1)) * NN;
            n0 = *reinterpret_cast<const uint4*>(np);
            n1 = *reinterpret_cast<const uint4*>(np + (size_t)NN);
            n2 = *reinterpret_cast<const uint4*>(np + (size_t)2 * NN);
            n3 = *reinterpret_cast<const uint4*>(np + (size_t)3 * NN);
        }
        // phase 1: per-lane partial row sums -> wave reduce -> LDS
        float p0 = dot16p(k0, vv);
        float p1 = dot16p(k1, vv);
        float p2 = dot16p(k2, vv);
        float p3 = dot16p(k3, vv);
#pragma unroll
        for (int off = 32; off > 0; off >>= 1) {
            p0 += __shfl_down(p0, off);
            p1 += __shfl_down(p1, off);
            p2 += __shfl_down(p2, off);
            p3 += __shfl_down(p3, off);
        }
        if (lane == 0) {
            red[g][w][0] = p0; red[g][w][1] = p1;
            red[g][w][2] = p2; red[g][w][3] = p3;
        }
        __syncthreads();
        // every wave computes u for the 4 rows (identical fp math, no 2nd sync)
        float ug[4];
#pragma unroll
        for (int r = 0; r < 4; r++) {
            float s = 0.f;
#pragma unroll
            for (int ww = 0; ww < 8; ww++) s += red[g][ww][r];
            ug[r] = kMass / (s * kInvSc + kStab);
        }
        if (!last) {
            // phase 2: re-convert the SAME registers, accumulate column partials
            axpy16p(k0, ug[0], ca);
            axpy16p(k1, ug[1], ca);
            axpy16p(k2, ug[2], ca);
            axpy16p(k3, ug[3], ca);
        } else {
            // final iteration: accumulate wsum terms from the same registers
            dacc += (double)ug[0] * (double)wsum16(k0, vv, glut);
            dacc += (double)ug[1] * (double)wsum16(k1, vv, glut);
            dacc += (double)ug[2] * (double)wsum16(k2, vv, glut);
            dacc += (double)ug[3] * (double)wsum16(k3, vv, glut);
        }
    }
    if (last) {
        for (int off = 32; off > 0; off >>= 1) dacc += __shfl_down(dacc, off);
        if (lane == 0) wred[w] = dacc;
        __syncthreads();
        if (t == 0) {
            double tot = 0.0;
#pragma unroll
            for (int i = 0; i < 8; i++) tot += wred[i];
            atomicAdd(&wacc[z], -(double)kEps * (double)kInvSc * tot);
        }
        return;
    }

    // ---- direct drain: pack this lane's 16 contiguous cols to bf16, 2x uint4
    unsigned short* rp = rcp + ((size_t)z * 256 + blockIdx.x) * NN + c0 + 16 * lane;
    uint4 o0, o1;
    o0.x = bf16pk(ca[0].x, ca[0].y); o0.y = bf16pk(ca[1].x, ca[1].y);
    o0.z = bf16pk(ca[2].x, ca[2].y); o0.w = bf16pk(ca[3].x, ca[3].y);
    o1.x = bf16pk(ca[4].x, ca[4].y); o1.y = bf16pk(ca[5].x, ca[5].y);
    o1.z = bf16pk(ca[6].x, ca[6].y); o1.w = bf16pk(ca[7].x, ca[7].y);
    *reinterpret_cast<uint4*>(rp)     = o0;
    *reinterpret_cast<uint4*>(rp + 8) = o1;
}

// -------------------------------- fold 256 bf16 block partials -> v (next iteration)
__global__ __launch_bounds__(256) void sk_reduce(const unsigned short* __restrict__ rcp,
                                                 float* __restrict__ v_out) {
    __shared__ float red[32 * 64];
    const int t = threadIdx.x, g = t & 7, q = t >> 3;
    const int z = blockIdx.z;
    const int c0 = blockIdx.x * 64;
    const unsigned short* base = rcp + (size_t)z * 256 * NN + c0 + 8 * g;
    float acc[8] = {};
#pragma unroll
    for (int r = 0; r < 8; r++) {
        uint4 hv = *reinterpret_cast<const uint4*>(base + (size_t)(8 * q + r) * NN);
        const unsigned int h[4] = {hv.x, hv.y, hv.z, hv.w};
#pragma unroll
        for (int j = 0; j < 4; j++) {
            acc[2 * j]     += __uint_as_float((h[j] & 0xFFFFu) << 16);
            acc[2 * j + 1] += __uint_as_float(h[j] & 0xFFFF0000u);
        }
    }
    float* rw = &red[q * 64 + g * 8];
    *reinterpret_cast<float4*>(rw)     = {acc[0], acc[1], acc[2], acc[3]};
    *reinterpret_cast<float4*>(rw + 4) = {acc[4], acc[5], acc[6], acc[7]};
    __syncthreads();
    if (t < 64) {
        float s = 0.f;
#pragma unroll 8
        for (int q2 = 0; q2 < 32; q2++) s += red[q2 * 64 + t];
        v_out[(size_t)z * NN + c0 + t] =
            kMass * __builtin_amdgcn_rcpf(fmaf(s, kInvSc, kStab));
    }
}

// ------------------------------------------------- combine
__global__ void sk_combine(const double* __restrict__ acc, float* __restrict__ out) {
    if (threadIdx.x == 0)
        out[0] = (float)((acc[0] - 0.5 * acc[1] - 0.5 * acc[2]) / 8192.0);
}

extern "C" void kernel_launch(void* const* d_in, const int* in_sizes, int n_in,
                              void* d_out, int out_size, void* d_ws, size_t ws_size,
                              hipStream_t stream) {
    const float* src = (const float*)d_in[0];
    const float* tgt = (const float*)d_in[1];
    float* out = (float*)d_out;
    char* ws = (char*)d_ws;

    // batched needs: 3 K matrices + 3x256x8192 bf16 partials + vectors
    const size_t need3 = 3ull * NN * NN + 3ull * 256 * NN * 2 + 8ull * NN * 4 + 1024;
    const bool batched = ws_size >= need3;
    const int B = batched ? 3 : 1;

    unsigned char*  K8  = (unsigned char*)ws;
    unsigned short* rcp = (unsigned short*)(ws + (size_t)B * NN * NN);
    float*  vb   = (float*)((char*)rcp + (size_t)B * 256 * NN * 2);
    float*  rc0  = vb + (size_t)B * NN;
    double* wacc = (double*)(rc0 + (size_t)B * NN);

    hipMemsetAsync(wacc, 0, 3 * sizeof(double), stream);

    if (batched) {
        hipMemsetAsync(rc0, 0, 3ull * NN * sizeof(float), stream);
        sk_build_k<<<dim3(64, 64, 3), 256, 0, stream>>>(src, tgt, K8, rc0, 3);
        sk_v<<<dim3(32, 1, 3), 256, 0, stream>>>(rc0, vb);           // v_1
        for (int t = 1; t <= 100; t++) {
            sk_iter<<<dim3(256, 1, 3), 512, 0, stream>>>(K8, vb, rcp, wacc,
                                                         t == 100 ? 1 : 0);
            if (t < 100)
                sk_reduce<<<dim3(128, 1, 3), 256, 0, stream>>>(rcp, vb);
        }
        // last sk_iter accumulated the transport costs into wacc[0..2]
    } else {
        const float* pts[3][2] = {{src, tgt}, {src, src}, {tgt, tgt}};
        for (int tf = 0; tf < 3; tf++) {
            hipMemsetAsync(rc0, 0, 1ull * NN * sizeof(float), stream);
            sk_build_k<<<dim3(64, 64, 1), 256, 0, stream>>>(pts[tf][0], pts[tf][1],
                                                            K8, rc0, 1);
            sk_v<<<dim3(32, 1, 1), 256, 0, stream>>>(rc0, vb);
            for (int t = 1; t <= 100; t++) {
                sk_iter<<<dim3(256, 1, 1), 512, 0, stream>>>(K8, vb, rcp, &wacc[tf],
                                                             t == 100 ? 1 : 0);
                if (t < 100)
                    sk_reduce<<<dim3(128, 1, 1), 256, 0, stream>>>(rcp, vb);
            }
        }
    }
    sk_combine<<<1, 64, 0, stream>>>(wacc, out);
}